// Round 3
// baseline (215.657 us; speedup 1.0000x reference)
//
#include <hip/hip_runtime.h>

// Bilinear warp, border value 0. image (32,3,384,512) fp32 NCHW.
// Two-pass: (1) repack image -> bf16 NHWC padded to 4ch (8 B/px) in d_ws;
// (2) warp: per pixel ONE 16B gather per row covers both x-taps x all 3 ch.
// R7: warp = 8 px/thread, 64x32 tile, per-CU vertical column walk.
//  - 16 gathers in flight/wave (2x R6) to cover L2-hit latency
//  - slot -> (column, step): each CU walks one 64px-wide column downward,
//    sliding gather window with ~75% overlap between steps (L1/L2 reuse)
//  - fixed costs (flow loads, stores) amortized over 8 px

#define NN 32
#define CC 3
#define HH 384
#define WW 512
#define HWSZ (HH * WW)

typedef float v4f __attribute__((ext_vector_type(4)));
typedef float v2f __attribute__((ext_vector_type(2)));
typedef unsigned short v8u __attribute__((ext_vector_type(8), aligned(8)));

__device__ __forceinline__ unsigned short f2bf(float x) {
    unsigned int u = __float_as_uint(x);
    unsigned int r = (u + 0x7FFFu + ((u >> 16) & 1u)) >> 16;   // RNE
    return (unsigned short)r;
}
__device__ __forceinline__ float bf2f(unsigned short b) {
    return __uint_as_float(((unsigned int)b) << 16);
}

// ---- pass 1: NCHW fp32 -> NHWC(pad4) bf16, 4 px/thread, streaming ----
__global__ __launch_bounds__(256) void prep_kernel(
    const float* __restrict__ image, unsigned short* __restrict__ ws)
{
    int t = blockIdx.x * 256 + threadIdx.x;
    int idx4 = t * 4;                      // first pixel (global over N*HW)
    int n = idx4 / HWSZ;
    int p = idx4 - n * HWSZ;
    const float* base = image + (size_t)n * CC * HWSZ;
    v4f c0 = __builtin_nontemporal_load((const v4f*)(base + p));
    v4f c1 = __builtin_nontemporal_load((const v4f*)(base + HWSZ + p));
    v4f c2 = __builtin_nontemporal_load((const v4f*)(base + 2 * HWSZ + p));
    v8u o0 = { f2bf(c0.x), f2bf(c1.x), f2bf(c2.x), 0,
               f2bf(c0.y), f2bf(c1.y), f2bf(c2.y), 0 };
    v8u o1 = { f2bf(c0.z), f2bf(c1.z), f2bf(c2.z), 0,
               f2bf(c0.w), f2bf(c1.w), f2bf(c2.w), 0 };
    // cached stores on purpose: ws should land in L2/L3 for the warp pass
    unsigned short* w = ws + (size_t)idx4 * 4;
    *(v8u*)(w)     = o0;
    *(v8u*)(w + 8) = o1;
}

// ---- pass 2: warp from bf16 NHWC, 8 px/thread, 64x32 tile/block ----
// grid = NN*HWSZ/2048 = 3072 blocks; XCD slab on low 3 bits.
// Within a slab: grp = slot&31 -> one of 32 columns (4 img x 8 tile-cols),
// step = slot>>5 -> vertical position. CU c gets slots c, c+32, ... so each
// CU walks ONE column top to bottom.
__global__ __launch_bounds__(256) void warp_kernel(
    const unsigned short* __restrict__ ws,
    const float* __restrict__ flow,
    float* __restrict__ out)
{
    int bid  = blockIdx.x;
    int slot = bid >> 3;                   // 0..383 within XCD slab
    int grp  = slot & 31;                  // column id: 4 img x 8 tile-cols
    int step = slot >> 5;                  // 0..11 vertical step (32 px each)
    int img  = grp >> 3;                   // image within slab
    int tx   = grp & 7;                    // tile column (64 px wide)
    int n    = (bid & 7) * 4 + img;

    int r = (int)threadIdx.x >> 3;                 // 0..31 row within tile
    int y = step * 32 + r;
    int x = (tx << 6) + (((int)threadIdx.x & 7) << 3); // 8 px per thread
    int p = y * WW + x;

    const float* fl = flow + (size_t)n * 2 * HWSZ;
    v4f fuA = __builtin_nontemporal_load((const v4f*)(fl + p));
    v4f fuB = __builtin_nontemporal_load((const v4f*)(fl + p + 4));
    v4f fvA = __builtin_nontemporal_load((const v4f*)(fl + HWSZ + p));
    v4f fvB = __builtin_nontemporal_load((const v4f*)(fl + HWSZ + p + 4));

    const unsigned short* wb = ws + (size_t)n * HWSZ * 4;
    float*                o  = out + (size_t)n * CC * HWSZ;

    int   rb0[8], rb1[8];
    float wx0[8], wx1[8], evv[8], dvv[8];

#pragma unroll
    for (int i = 0; i < 8; ++i) {
        float fu = (i < 4) ? fuA[i & 3] : fuB[i & 3];
        float fv = (i < 4) ? fvA[i & 3] : fvB[i & 3];
        float u = (float)(x + i) + fu * (float)WW;
        float v = (float)y       + fv * (float)HH;
        float u0 = floorf(u), v0 = floorf(v);
        float du = u - u0,    dv = v - v0;
        int u0i = (int)u0, v0i = (int)v0;
        bool valid = (u >= 0.f) && (u <= (float)(WW - 1)) &&
                     (v >= 0.f) && (v <= (float)(HH - 1));
        int x0 = min(max(u0i,     0), WW - 1);
        int x1 = min(max(u0i + 1, 0), WW - 1);
        int xb = min(x0, WW - 2);          // 16B pair never crosses row end
        int y0 = min(max(v0i,     0), HH - 1);
        int y1 = min(max(v0i + 1, 0), HH - 1);
        bool h0 = (x0 > xb);
        bool h1 = (x1 > xb);
        float eu = 1.f - du;
        // fold lo/hi tap select into horizontal weights (eu+du == 1)
        float w0 = (h0 ? 0.f : eu) + (h1 ? 0.f : du);
        wx0[i] = w0;
        wx1[i] = 1.f - w0;
        float ev = 1.f - dv;
        evv[i] = valid ? ev : 0.f;         // fold border-zero into row weights
        dvv[i] = valid ? dv : 0.f;
        rb0[i] = y0 * WW + xb;
        rb1[i] = y1 * WW + xb;
    }

    // issue all 16 gathers back-to-back (latency hiding via ILP)
    v8u A[8], B[8];
#pragma unroll
    for (int i = 0; i < 8; ++i) {
        A[i] = *(const v8u*)(wb + (size_t)rb0[i] * 4);
        B[i] = *(const v8u*)(wb + (size_t)rb1[i] * 4);
    }

    v4f r0a, r0b, r1a, r1b, r2a, r2b;
    float* rc[3][2] = { { (float*)&r0a, (float*)&r0b },
                        { (float*)&r1a, (float*)&r1b },
                        { (float*)&r2a, (float*)&r2b } };
#pragma unroll
    for (int i = 0; i < 8; ++i) {
#pragma unroll
        for (int c = 0; c < CC; ++c) {
            float aLo = bf2f(A[i][c]),     aHi = bf2f(A[i][4 + c]);
            float bLo = bf2f(B[i][c]),     bHi = bf2f(B[i][4 + c]);
            float ra = wx0[i] * aLo + wx1[i] * aHi;
            float rb = wx0[i] * bLo + wx1[i] * bHi;
            rc[c][i >> 2][i & 3] = ra * evv[i] + rb * dvv[i];
        }
    }

    __builtin_nontemporal_store(r0a, (v4f*)(o + p));
    __builtin_nontemporal_store(r0b, (v4f*)(o + p + 4));
    __builtin_nontemporal_store(r1a, (v4f*)(o + HWSZ + p));
    __builtin_nontemporal_store(r1b, (v4f*)(o + HWSZ + p + 4));
    __builtin_nontemporal_store(r2a, (v4f*)(o + 2 * HWSZ + p));
    __builtin_nontemporal_store(r2b, (v4f*)(o + 2 * HWSZ + p + 4));
}

// ---- fallback (R3 kernel) if ws is too small ----
__global__ __launch_bounds__(256) void warp_fb(
    const float* __restrict__ image,
    const float* __restrict__ flow,
    float* __restrict__ out)
{
    int bid  = blockIdx.x;
    int slot = bid >> 3;
    int img  = slot / (HWSZ / 1024);
    int wi   = slot - img * (HWSZ / 1024);
    int n    = (bid & 7) * 4 + img;

    int p = wi * 1024 + (int)threadIdx.x * 4;
    int y = p >> 9;
    int x = p & (WW - 1);

    const float* fl = flow + (size_t)n * 2 * HWSZ;
    v4f fu4 = __builtin_nontemporal_load((const v4f*)(fl + p));
    v4f fv4 = __builtin_nontemporal_load((const v4f*)(fl + HWSZ + p));

    float u[4] = { (float)(x + 0) + fu4.x * (float)WW,
                   (float)(x + 1) + fu4.y * (float)WW,
                   (float)(x + 2) + fu4.z * (float)WW,
                   (float)(x + 3) + fu4.w * (float)WW };
    float v[4] = { (float)y + fv4.x * (float)HH,
                   (float)y + fv4.y * (float)HH,
                   (float)y + fv4.z * (float)HH,
                   (float)y + fv4.w * (float)HH };
    int rb0[4], rb1[4];
    float w00[4], w10[4], w01[4], w11[4];
    bool hi0[4], hi1[4], valid[4];
#pragma unroll
    for (int i = 0; i < 4; ++i) {
        float u0 = floorf(u[i]), v0 = floorf(v[i]);
        float du = u[i] - u0, dv = v[i] - v0;
        int u0i = (int)u0, v0i = (int)v0;
        valid[i] = (u[i] >= 0.f) && (u[i] <= (float)(WW - 1)) &&
                   (v[i] >= 0.f) && (v[i] <= (float)(HH - 1));
        int x0 = min(max(u0i, 0), WW - 1);
        int x1 = min(max(u0i + 1, 0), WW - 1);
        int xb = min(x0, WW - 2);
        int y0 = min(max(v0i, 0), HH - 1);
        int y1 = min(max(v0i + 1, 0), HH - 1);
        rb0[i] = y0 * WW + xb; rb1[i] = y1 * WW + xb;
        hi0[i] = (x0 > xb); hi1[i] = (x1 > xb);
        float eu = 1.f - du, ev = 1.f - dv;
        w00[i] = eu * ev; w10[i] = du * ev; w01[i] = eu * dv; w11[i] = du * dv;
    }
    const float* imb = image + (size_t)n * CC * HWSZ;
    float*       o   = out   + (size_t)n * CC * HWSZ;
    v2f a[CC][4], b[CC][4];
#pragma unroll
    for (int c = 0; c < CC; ++c) {
        const float* ic = imb + c * HWSZ;
#pragma unroll
        for (int i = 0; i < 4; ++i) {
            a[c][i] = *(const v2f*)(ic + rb0[i]);
            b[c][i] = *(const v2f*)(ic + rb1[i]);
        }
    }
#pragma unroll
    for (int c = 0; c < CC; ++c) {
        v4f r;
#pragma unroll
        for (int i = 0; i < 4; ++i) {
            float g00 = hi0[i] ? a[c][i].y : a[c][i].x;
            float g10 = hi1[i] ? a[c][i].y : a[c][i].x;
            float g01 = hi0[i] ? b[c][i].y : b[c][i].x;
            float g11 = hi1[i] ? b[c][i].y : b[c][i].x;
            float res = w00[i] * g00 + w10[i] * g10 + w01[i] * g01 + w11[i] * g11;
            r[i] = valid[i] ? res : 0.f;
        }
        __builtin_nontemporal_store(r, (v4f*)(o + c * HWSZ + p));
    }
}

extern "C" void kernel_launch(void* const* d_in, const int* in_sizes, int n_in,
                              void* d_out, int out_size, void* d_ws, size_t ws_size,
                              hipStream_t stream) {
    const float* image = (const float*)d_in[0];
    const float* flow  = (const float*)d_in[1];
    float* out = (float*)d_out;

    const size_t need = (size_t)NN * HWSZ * 4 * sizeof(unsigned short); // 50.3 MB
    if (ws_size >= need) {
        unsigned short* ws = (unsigned short*)d_ws;
        prep_kernel<<<NN * HWSZ / (256 * 4), 256, 0, stream>>>(image, ws);
        warp_kernel<<<NN * HWSZ / 2048, 256, 0, stream>>>(ws, flow, out); // 3072 blocks
    } else {
        warp_fb<<<NN * HWSZ / 1024, 256, 0, stream>>>(image, flow, out);
    }
}

// Round 5
// 205.459 us; speedup vs baseline: 1.0496x; 1.0496x over previous
//
#include <hip/hip_runtime.h>

// Bilinear warp, border value 0. image (32,3,384,512) fp32 NCHW.
// Two-pass: (1) repack image -> bf16 NHWC padded to 4ch (8 B/px) in d_ws;
// (2) warp: per pixel ONE 16B gather per row covers both x-taps x all 3 ch.
// R8 (resubmit; previous round hit GPU acquisition timeout):
// revert to R6 geometry (64x16 tile, 4 px/thread — best measured 60us).
// Scalarize warp inner code: no arrays / pointer tables (R6 had float* rc[3]
// and A[4]/B[4] arrays -> compiler rolled loads, VGPR=36, ~2 loads in flight).
// 8 named gathers issued back-to-back so all stay outstanding (MLP fix).

#define NN 32
#define CC 3
#define HH 384
#define WW 512
#define HWSZ (HH * WW)

typedef float v4f __attribute__((ext_vector_type(4)));
typedef float v2f __attribute__((ext_vector_type(2)));
typedef unsigned short v8u __attribute__((ext_vector_type(8), aligned(8)));

__device__ __forceinline__ unsigned short f2bf(float x) {
    unsigned int u = __float_as_uint(x);
    unsigned int r = (u + 0x7FFFu + ((u >> 16) & 1u)) >> 16;   // RNE
    return (unsigned short)r;
}
__device__ __forceinline__ float bf2f(unsigned short b) {
    return __uint_as_float(((unsigned int)b) << 16);
}

// ---- pass 1: NCHW fp32 -> NHWC(pad4) bf16, 4 px/thread, streaming ----
__global__ __launch_bounds__(256) void prep_kernel(
    const float* __restrict__ image, unsigned short* __restrict__ ws)
{
    int t = blockIdx.x * 256 + threadIdx.x;
    int idx4 = t * 4;                      // first pixel (global over N*HW)
    int n = idx4 / HWSZ;
    int p = idx4 - n * HWSZ;
    const float* base = image + (size_t)n * CC * HWSZ;
    v4f c0 = __builtin_nontemporal_load((const v4f*)(base + p));
    v4f c1 = __builtin_nontemporal_load((const v4f*)(base + HWSZ + p));
    v4f c2 = __builtin_nontemporal_load((const v4f*)(base + 2 * HWSZ + p));
    v8u o0 = { f2bf(c0.x), f2bf(c1.x), f2bf(c2.x), 0,
               f2bf(c0.y), f2bf(c1.y), f2bf(c2.y), 0 };
    v8u o1 = { f2bf(c0.z), f2bf(c1.z), f2bf(c2.z), 0,
               f2bf(c0.w), f2bf(c1.w), f2bf(c2.w), 0 };
    // cached stores on purpose: ws should land in L2/L3 for the warp pass
    unsigned short* w = ws + (size_t)idx4 * 4;
    *(v8u*)(w)     = o0;
    *(v8u*)(w + 8) = o1;
}

// ---- pass 2: warp from bf16 NHWC, 4 px/thread, 64x16 tile/block ----
// grid = NN*HWSZ/1024 = 6144 blocks; XCD-slab swizzle on low 3 bits.
__global__ __launch_bounds__(256) void warp_kernel(
    const unsigned short* __restrict__ ws,
    const float* __restrict__ flow,
    float* __restrict__ out)
{
    int bid  = blockIdx.x;
    int slot = bid >> 3;                   // 0..767 within XCD slab
    int img  = slot / 192;                 // 192 tiles per image (8x24)
    int tile = slot - img * 192;
    int n    = (bid & 7) * 4 + img;        // 4 images per XCD slab
    int ty   = tile >> 3;                  // 24 tile-rows (16 px tall)
    int tx   = tile & 7;                   // 8 tile-cols (64 px wide)

    int r = (int)threadIdx.x >> 4;                  // 0..15 row within tile
    int y = ty * 16 + r;
    int x = (tx << 6) + (((int)threadIdx.x & 15) << 2); // 4 px per thread
    int p = y * WW + x;

    const float* fl = flow + (size_t)n * 2 * HWSZ;
    v4f fu4 = __builtin_nontemporal_load((const v4f*)(fl + p));
    v4f fv4 = __builtin_nontemporal_load((const v4f*)(fl + HWSZ + p));

    const unsigned short* wb = ws + (size_t)n * HWSZ * 4;
    float*                o  = out + (size_t)n * CC * HWSZ;

    // ---- fully scalarized per-pixel address/weight computation ----
#define ADDR(i)                                                               \
    int rb0_##i, rb1_##i; float wx0_##i, wx1_##i, ev_##i, dv_##i;             \
    {                                                                         \
        float u  = (float)(x + i) + fu4[i] * (float)WW;                       \
        float v  = (float)y       + fv4[i] * (float)HH;                       \
        float u0 = floorf(u), v0 = floorf(v);                                 \
        float du = u - u0,    dvf = v - v0;                                   \
        int u0i = (int)u0, v0i = (int)v0;                                     \
        bool valid = (u >= 0.f) && (u <= (float)(WW - 1)) &&                  \
                     (v >= 0.f) && (v <= (float)(HH - 1));                    \
        int x0 = min(max(u0i,     0), WW - 1);                                \
        int x1 = min(max(u0i + 1, 0), WW - 1);                                \
        int xb = min(x0, WW - 2);        /* 16B pair never crosses row end */ \
        int y0 = min(max(v0i,     0), HH - 1);                                \
        int y1 = min(max(v0i + 1, 0), HH - 1);                                \
        float eu = 1.f - du;                                                  \
        float w0 = ((x0 > xb) ? 0.f : eu) + ((x1 > xb) ? 0.f : du);           \
        wx0_##i = w0;                                                         \
        wx1_##i = 1.f - w0;              /* eu+du == 1 */                     \
        float evq = 1.f - dvf;                                                \
        ev_##i = valid ? evq : 0.f;      /* fold border-zero into weights */  \
        dv_##i = valid ? dvf : 0.f;                                           \
        rb0_##i = y0 * WW + xb;                                               \
        rb1_##i = y1 * WW + xb;                                               \
    }

    ADDR(0) ADDR(1) ADDR(2) ADDR(3)

    // ---- issue all 8 gathers back-to-back; named regs keep them in flight --
    v8u A0 = *(const v8u*)(wb + (size_t)rb0_0 * 4);
    v8u B0 = *(const v8u*)(wb + (size_t)rb1_0 * 4);
    v8u A1 = *(const v8u*)(wb + (size_t)rb0_1 * 4);
    v8u B1 = *(const v8u*)(wb + (size_t)rb1_1 * 4);
    v8u A2 = *(const v8u*)(wb + (size_t)rb0_2 * 4);
    v8u B2 = *(const v8u*)(wb + (size_t)rb1_2 * 4);
    v8u A3 = *(const v8u*)(wb + (size_t)rb0_3 * 4);
    v8u B3 = *(const v8u*)(wb + (size_t)rb1_3 * 4);

    v4f r0, r1, r2;
#define BLEND(i, Ai, Bi)                                                      \
    {                                                                         \
        float aL, aH, bL, bH, ra, rb;                                         \
        aL = bf2f(Ai[0]); aH = bf2f(Ai[4]);                                   \
        bL = bf2f(Bi[0]); bH = bf2f(Bi[4]);                                   \
        ra = wx0_##i * aL + wx1_##i * aH;                                     \
        rb = wx0_##i * bL + wx1_##i * bH;                                     \
        r0[i] = ra * ev_##i + rb * dv_##i;                                    \
        aL = bf2f(Ai[1]); aH = bf2f(Ai[5]);                                   \
        bL = bf2f(Bi[1]); bH = bf2f(Bi[5]);                                   \
        ra = wx0_##i * aL + wx1_##i * aH;                                     \
        rb = wx0_##i * bL + wx1_##i * bH;                                     \
        r1[i] = ra * ev_##i + rb * dv_##i;                                    \
        aL = bf2f(Ai[2]); aH = bf2f(Ai[6]);                                   \
        bL = bf2f(Bi[2]); bH = bf2f(Bi[6]);                                   \
        ra = wx0_##i * aL + wx1_##i * aH;                                     \
        rb = wx0_##i * bL + wx1_##i * bH;                                     \
        r2[i] = ra * ev_##i + rb * dv_##i;                                    \
    }

    BLEND(0, A0, B0)
    BLEND(1, A1, B1)
    BLEND(2, A2, B2)
    BLEND(3, A3, B3)

    __builtin_nontemporal_store(r0, (v4f*)(o + p));
    __builtin_nontemporal_store(r1, (v4f*)(o + HWSZ + p));
    __builtin_nontemporal_store(r2, (v4f*)(o + 2 * HWSZ + p));
#undef ADDR
#undef BLEND
}

// ---- fallback (R3 kernel) if ws is too small ----
__global__ __launch_bounds__(256) void warp_fb(
    const float* __restrict__ image,
    const float* __restrict__ flow,
    float* __restrict__ out)
{
    int bid  = blockIdx.x;
    int slot = bid >> 3;
    int img  = slot / (HWSZ / 1024);
    int wi   = slot - img * (HWSZ / 1024);
    int n    = (bid & 7) * 4 + img;

    int p = wi * 1024 + (int)threadIdx.x * 4;
    int y = p >> 9;
    int x = p & (WW - 1);

    const float* fl = flow + (size_t)n * 2 * HWSZ;
    v4f fu4 = __builtin_nontemporal_load((const v4f*)(fl + p));
    v4f fv4 = __builtin_nontemporal_load((const v4f*)(fl + HWSZ + p));

    float u[4] = { (float)(x + 0) + fu4.x * (float)WW,
                   (float)(x + 1) + fu4.y * (float)WW,
                   (float)(x + 2) + fu4.z * (float)WW,
                   (float)(x + 3) + fu4.w * (float)WW };
    float v[4] = { (float)y + fv4.x * (float)HH,
                   (float)y + fv4.y * (float)HH,
                   (float)y + fv4.z * (float)HH,
                   (float)y + fv4.w * (float)HH };
    int rb0[4], rb1[4];
    float w00[4], w10[4], w01[4], w11[4];
    bool hi0[4], hi1[4], valid[4];
#pragma unroll
    for (int i = 0; i < 4; ++i) {
        float u0 = floorf(u[i]), v0 = floorf(v[i]);
        float du = u[i] - u0, dv = v[i] - v0;
        int u0i = (int)u0, v0i = (int)v0;
        valid[i] = (u[i] >= 0.f) && (u[i] <= (float)(WW - 1)) &&
                   (v[i] >= 0.f) && (v[i] <= (float)(HH - 1));
        int x0 = min(max(u0i, 0), WW - 1);
        int x1 = min(max(u0i + 1, 0), WW - 1);
        int xb = min(x0, WW - 2);
        int y0 = min(max(v0i, 0), HH - 1);
        int y1 = min(max(v0i + 1, 0), HH - 1);
        rb0[i] = y0 * WW + xb; rb1[i] = y1 * WW + xb;
        hi0[i] = (x0 > xb); hi1[i] = (x1 > xb);
        float eu = 1.f - du, ev = 1.f - dv;
        w00[i] = eu * ev; w10[i] = du * ev; w01[i] = eu * dv; w11[i] = du * dv;
    }
    const float* imb = image + (size_t)n * CC * HWSZ;
    float*       o   = out   + (size_t)n * CC * HWSZ;
    v2f a[CC][4], b[CC][4];
#pragma unroll
    for (int c = 0; c < CC; ++c) {
        const float* ic = imb + c * HWSZ;
#pragma unroll
        for (int i = 0; i < 4; ++i) {
            a[c][i] = *(const v2f*)(ic + rb0[i]);
            b[c][i] = *(const v2f*)(ic + rb1[i]);
        }
    }
#pragma unroll
    for (int c = 0; c < CC; ++c) {
        v4f r;
#pragma unroll
        for (int i = 0; i < 4; ++i) {
            float g00 = hi0[i] ? a[c][i].y : a[c][i].x;
            float g10 = hi1[i] ? a[c][i].y : a[c][i].x;
            float g01 = hi0[i] ? b[c][i].y : b[c][i].x;
            float g11 = hi1[i] ? b[c][i].y : b[c][i].x;
            float res = w00[i] * g00 + w10[i] * g10 + w01[i] * g01 + w11[i] * g11;
            r[i] = valid[i] ? res : 0.f;
        }
        __builtin_nontemporal_store(r, (v4f*)(o + c * HWSZ + p));
    }
}

extern "C" void kernel_launch(void* const* d_in, const int* in_sizes, int n_in,
                              void* d_out, int out_size, void* d_ws, size_t ws_size,
                              hipStream_t stream) {
    const float* image = (const float*)d_in[0];
    const float* flow  = (const float*)d_in[1];
    float* out = (float*)d_out;

    const size_t need = (size_t)NN * HWSZ * 4 * sizeof(unsigned short); // 50.3 MB
    if (ws_size >= need) {
        unsigned short* ws = (unsigned short*)d_ws;
        prep_kernel<<<NN * HWSZ / (256 * 4), 256, 0, stream>>>(image, ws);
        warp_kernel<<<NN * HWSZ / 1024, 256, 0, stream>>>(ws, flow, out); // 6144 blocks
    } else {
        warp_fb<<<NN * HWSZ / 1024, 256, 0, stream>>>(image, flow, out);
    }
}

// Round 6
// 201.167 us; speedup vs baseline: 1.0720x; 1.0213x over previous
//
#include <hip/hip_runtime.h>

// Bilinear warp, border value 0. image (32,3,384,512) fp32 NCHW.
// Two-pass: (1) repack image -> bf16 NHWC padded to 4ch (8 B/px) in d_ws;
// (2) warp: per pixel ONE 16B gather per row covers both x-taps x all 3 ch.
// R9: R8 + sched_barrier(0) fences around the 8-gather cluster.
// R8 post-mortem: VGPR stayed 36 -> scheduler re-serialized the loads into
// issue/wait/consume pairs (2 in flight). Source order can't force MLP;
// sched_barrier regions can: [addr math] | [8 loads] | [blends] pins all 8
// loads outstanding -> incremental vmcnt(6/4/2/0) drain in the blend region.

#define NN 32
#define CC 3
#define HH 384
#define WW 512
#define HWSZ (HH * WW)

typedef float v4f __attribute__((ext_vector_type(4)));
typedef float v2f __attribute__((ext_vector_type(2)));
typedef unsigned short v8u __attribute__((ext_vector_type(8), aligned(8)));

__device__ __forceinline__ unsigned short f2bf(float x) {
    unsigned int u = __float_as_uint(x);
    unsigned int r = (u + 0x7FFFu + ((u >> 16) & 1u)) >> 16;   // RNE
    return (unsigned short)r;
}
__device__ __forceinline__ float bf2f(unsigned short b) {
    return __uint_as_float(((unsigned int)b) << 16);
}

// ---- pass 1: NCHW fp32 -> NHWC(pad4) bf16, 4 px/thread, streaming ----
__global__ __launch_bounds__(256) void prep_kernel(
    const float* __restrict__ image, unsigned short* __restrict__ ws)
{
    int t = blockIdx.x * 256 + threadIdx.x;
    int idx4 = t * 4;                      // first pixel (global over N*HW)
    int n = idx4 / HWSZ;
    int p = idx4 - n * HWSZ;
    const float* base = image + (size_t)n * CC * HWSZ;
    v4f c0 = __builtin_nontemporal_load((const v4f*)(base + p));
    v4f c1 = __builtin_nontemporal_load((const v4f*)(base + HWSZ + p));
    v4f c2 = __builtin_nontemporal_load((const v4f*)(base + 2 * HWSZ + p));
    v8u o0 = { f2bf(c0.x), f2bf(c1.x), f2bf(c2.x), 0,
               f2bf(c0.y), f2bf(c1.y), f2bf(c2.y), 0 };
    v8u o1 = { f2bf(c0.z), f2bf(c1.z), f2bf(c2.z), 0,
               f2bf(c0.w), f2bf(c1.w), f2bf(c2.w), 0 };
    // cached stores on purpose: ws should land in L2/L3 for the warp pass
    unsigned short* w = ws + (size_t)idx4 * 4;
    *(v8u*)(w)     = o0;
    *(v8u*)(w + 8) = o1;
}

// ---- pass 2: warp from bf16 NHWC, 4 px/thread, 64x16 tile/block ----
// grid = NN*HWSZ/1024 = 6144 blocks; XCD-slab swizzle on low 3 bits.
__global__ __launch_bounds__(256) void warp_kernel(
    const unsigned short* __restrict__ ws,
    const float* __restrict__ flow,
    float* __restrict__ out)
{
    int bid  = blockIdx.x;
    int slot = bid >> 3;                   // 0..767 within XCD slab
    int img  = slot / 192;                 // 192 tiles per image (8x24)
    int tile = slot - img * 192;
    int n    = (bid & 7) * 4 + img;        // 4 images per XCD slab
    int ty   = tile >> 3;                  // 24 tile-rows (16 px tall)
    int tx   = tile & 7;                   // 8 tile-cols (64 px wide)

    int r = (int)threadIdx.x >> 4;                  // 0..15 row within tile
    int y = ty * 16 + r;
    int x = (tx << 6) + (((int)threadIdx.x & 15) << 2); // 4 px per thread
    int p = y * WW + x;

    const float* fl = flow + (size_t)n * 2 * HWSZ;
    v4f fu4 = __builtin_nontemporal_load((const v4f*)(fl + p));
    v4f fv4 = __builtin_nontemporal_load((const v4f*)(fl + HWSZ + p));

    const unsigned short* wb = ws + (size_t)n * HWSZ * 4;
    float*                o  = out + (size_t)n * CC * HWSZ;

    // ---- fully scalarized per-pixel address/weight computation ----
#define ADDR(i)                                                               \
    int rb0_##i, rb1_##i; float wx0_##i, wx1_##i, ev_##i, dv_##i;             \
    {                                                                         \
        float u  = (float)(x + i) + fu4[i] * (float)WW;                       \
        float v  = (float)y       + fv4[i] * (float)HH;                       \
        float u0 = floorf(u), v0 = floorf(v);                                 \
        float du = u - u0,    dvf = v - v0;                                   \
        int u0i = (int)u0, v0i = (int)v0;                                     \
        bool valid = (u >= 0.f) && (u <= (float)(WW - 1)) &&                  \
                     (v >= 0.f) && (v <= (float)(HH - 1));                    \
        int x0 = min(max(u0i,     0), WW - 1);                                \
        int x1 = min(max(u0i + 1, 0), WW - 1);                                \
        int xb = min(x0, WW - 2);        /* 16B pair never crosses row end */ \
        int y0 = min(max(v0i,     0), HH - 1);                                \
        int y1 = min(max(v0i + 1, 0), HH - 1);                                \
        float eu = 1.f - du;                                                  \
        float w0 = ((x0 > xb) ? 0.f : eu) + ((x1 > xb) ? 0.f : du);           \
        wx0_##i = w0;                                                         \
        wx1_##i = 1.f - w0;              /* eu+du == 1 */                     \
        float evq = 1.f - dvf;                                                \
        ev_##i = valid ? evq : 0.f;      /* fold border-zero into weights */  \
        dv_##i = valid ? dvf : 0.f;                                           \
        rb0_##i = y0 * WW + xb;                                               \
        rb1_##i = y1 * WW + xb;                                               \
    }

    ADDR(0) ADDR(1) ADDR(2) ADDR(3)

    // ---- region fence: cluster all 8 gathers so all stay outstanding ----
    __builtin_amdgcn_sched_barrier(0);
    v8u A0 = *(const v8u*)(wb + (size_t)rb0_0 * 4);
    v8u B0 = *(const v8u*)(wb + (size_t)rb1_0 * 4);
    v8u A1 = *(const v8u*)(wb + (size_t)rb0_1 * 4);
    v8u B1 = *(const v8u*)(wb + (size_t)rb1_1 * 4);
    v8u A2 = *(const v8u*)(wb + (size_t)rb0_2 * 4);
    v8u B2 = *(const v8u*)(wb + (size_t)rb1_2 * 4);
    v8u A3 = *(const v8u*)(wb + (size_t)rb0_3 * 4);
    v8u B3 = *(const v8u*)(wb + (size_t)rb1_3 * 4);
    __builtin_amdgcn_sched_barrier(0);

    v4f r0, r1, r2;
#define BLEND(i, Ai, Bi)                                                      \
    {                                                                         \
        float aL, aH, bL, bH, ra, rb;                                         \
        aL = bf2f(Ai[0]); aH = bf2f(Ai[4]);                                   \
        bL = bf2f(Bi[0]); bH = bf2f(Bi[4]);                                   \
        ra = wx0_##i * aL + wx1_##i * aH;                                     \
        rb = wx0_##i * bL + wx1_##i * bH;                                     \
        r0[i] = ra * ev_##i + rb * dv_##i;                                    \
        aL = bf2f(Ai[1]); aH = bf2f(Ai[5]);                                   \
        bL = bf2f(Bi[1]); bH = bf2f(Bi[5]);                                   \
        ra = wx0_##i * aL + wx1_##i * aH;                                     \
        rb = wx0_##i * bL + wx1_##i * bH;                                     \
        r1[i] = ra * ev_##i + rb * dv_##i;                                    \
        aL = bf2f(Ai[2]); aH = bf2f(Ai[6]);                                   \
        bL = bf2f(Bi[2]); bH = bf2f(Bi[6]);                                   \
        ra = wx0_##i * aL + wx1_##i * aH;                                     \
        rb = wx0_##i * bL + wx1_##i * bH;                                     \
        r2[i] = ra * ev_##i + rb * dv_##i;                                    \
    }

    BLEND(0, A0, B0)
    BLEND(1, A1, B1)
    BLEND(2, A2, B2)
    BLEND(3, A3, B3)

    __builtin_nontemporal_store(r0, (v4f*)(o + p));
    __builtin_nontemporal_store(r1, (v4f*)(o + HWSZ + p));
    __builtin_nontemporal_store(r2, (v4f*)(o + 2 * HWSZ + p));
#undef ADDR
#undef BLEND
}

// ---- fallback (R3 kernel) if ws is too small ----
__global__ __launch_bounds__(256) void warp_fb(
    const float* __restrict__ image,
    const float* __restrict__ flow,
    float* __restrict__ out)
{
    int bid  = blockIdx.x;
    int slot = bid >> 3;
    int img  = slot / (HWSZ / 1024);
    int wi   = slot - img * (HWSZ / 1024);
    int n    = (bid & 7) * 4 + img;

    int p = wi * 1024 + (int)threadIdx.x * 4;
    int y = p >> 9;
    int x = p & (WW - 1);

    const float* fl = flow + (size_t)n * 2 * HWSZ;
    v4f fu4 = __builtin_nontemporal_load((const v4f*)(fl + p));
    v4f fv4 = __builtin_nontemporal_load((const v4f*)(fl + HWSZ + p));

    float u[4] = { (float)(x + 0) + fu4.x * (float)WW,
                   (float)(x + 1) + fu4.y * (float)WW,
                   (float)(x + 2) + fu4.z * (float)WW,
                   (float)(x + 3) + fu4.w * (float)WW };
    float v[4] = { (float)y + fv4.x * (float)HH,
                   (float)y + fv4.y * (float)HH,
                   (float)y + fv4.z * (float)HH,
                   (float)y + fv4.w * (float)HH };
    int rb0[4], rb1[4];
    float w00[4], w10[4], w01[4], w11[4];
    bool hi0[4], hi1[4], valid[4];
#pragma unroll
    for (int i = 0; i < 4; ++i) {
        float u0 = floorf(u[i]), v0 = floorf(v[i]);
        float du = u[i] - u0, dv = v[i] - v0;
        int u0i = (int)u0, v0i = (int)v0;
        valid[i] = (u[i] >= 0.f) && (u[i] <= (float)(WW - 1)) &&
                   (v[i] >= 0.f) && (v[i] <= (float)(HH - 1));
        int x0 = min(max(u0i, 0), WW - 1);
        int x1 = min(max(u0i + 1, 0), WW - 1);
        int xb = min(x0, WW - 2);
        int y0 = min(max(v0i, 0), HH - 1);
        int y1 = min(max(v0i + 1, 0), HH - 1);
        rb0[i] = y0 * WW + xb; rb1[i] = y1 * WW + xb;
        hi0[i] = (x0 > xb); hi1[i] = (x1 > xb);
        float eu = 1.f - du, ev = 1.f - dv;
        w00[i] = eu * ev; w10[i] = du * ev; w01[i] = eu * dv; w11[i] = du * dv;
    }
    const float* imb = image + (size_t)n * CC * HWSZ;
    float*       o   = out   + (size_t)n * CC * HWSZ;
    v2f a[CC][4], b[CC][4];
#pragma unroll
    for (int c = 0; c < CC; ++c) {
        const float* ic = imb + c * HWSZ;
#pragma unroll
        for (int i = 0; i < 4; ++i) {
            a[c][i] = *(const v2f*)(ic + rb0[i]);
            b[c][i] = *(const v2f*)(ic + rb1[i]);
        }
    }
#pragma unroll
    for (int c = 0; c < CC; ++c) {
        v4f r;
#pragma unroll
        for (int i = 0; i < 4; ++i) {
            float g00 = hi0[i] ? a[c][i].y : a[c][i].x;
            float g10 = hi1[i] ? a[c][i].y : a[c][i].x;
            float g01 = hi0[i] ? b[c][i].y : b[c][i].x;
            float g11 = hi1[i] ? b[c][i].y : b[c][i].x;
            float res = w00[i] * g00 + w10[i] * g10 + w01[i] * g01 + w11[i] * g11;
            r[i] = valid[i] ? res : 0.f;
        }
        __builtin_nontemporal_store(r, (v4f*)(o + c * HWSZ + p));
    }
}

extern "C" void kernel_launch(void* const* d_in, const int* in_sizes, int n_in,
                              void* d_out, int out_size, void* d_ws, size_t ws_size,
                              hipStream_t stream) {
    const float* image = (const float*)d_in[0];
    const float* flow  = (const float*)d_in[1];
    float* out = (float*)d_out;

    const size_t need = (size_t)NN * HWSZ * 4 * sizeof(unsigned short); // 50.3 MB
    if (ws_size >= need) {
        unsigned short* ws = (unsigned short*)d_ws;
        prep_kernel<<<NN * HWSZ / (256 * 4), 256, 0, stream>>>(image, ws);
        warp_kernel<<<NN * HWSZ / 1024, 256, 0, stream>>>(ws, flow, out); // 6144 blocks
    } else {
        warp_fb<<<NN * HWSZ / 1024, 256, 0, stream>>>(image, flow, out);
    }
}

// Round 9
// 193.567 us; speedup vs baseline: 1.1141x; 1.0393x over previous
//
#include <hip/hip_runtime.h>

// Bilinear warp, border value 0. image (32,3,384,512) fp32 NCHW.
// Two-pass: (1) repack image -> bf16 NHWC padded to 4ch (8 B/px) in d_ws;
// (2) warp: per pixel ONE 16B gather per row covers both x-taps x all 3 ch.
// R11: single-asm-block MLP experiment. R10's 8 separate asm-volatile loads
// core-dumped (suspect: regalloc spill window between load asm and waitcnt
// asm touching not-yet-landed dest regs). Fuse all 8 global_load_dwordx4 +
// s_waitcnt vmcnt(0) into ONE asm block: atomic to compiler, no windows,
// forces 8 results (32 VGPR) simultaneously live -> true 8-deep MLP.

#define NN 32
#define CC 3
#define HH 384
#define WW 512
#define HWSZ (HH * WW)

typedef float v4f __attribute__((ext_vector_type(4)));
typedef float v2f __attribute__((ext_vector_type(2)));
typedef unsigned int v4u __attribute__((ext_vector_type(4)));
typedef unsigned short v8u __attribute__((ext_vector_type(8), aligned(8)));

__device__ __forceinline__ unsigned short f2bf(float x) {
    unsigned int u = __float_as_uint(x);
    unsigned int r = (u + 0x7FFFu + ((u >> 16) & 1u)) >> 16;   // RNE
    return (unsigned short)r;
}
__device__ __forceinline__ float bflo(unsigned int w) {       // bf16 in lo16
    return __uint_as_float(w << 16);
}
__device__ __forceinline__ float bfhi(unsigned int w) {       // bf16 in hi16
    return __uint_as_float(w & 0xFFFF0000u);
}

// ---- pass 1: NCHW fp32 -> NHWC(pad4) bf16, 4 px/thread, streaming ----
__global__ __launch_bounds__(256) void prep_kernel(
    const float* __restrict__ image, unsigned short* __restrict__ ws)
{
    int t = blockIdx.x * 256 + threadIdx.x;
    int idx4 = t * 4;                      // first pixel (global over N*HW)
    int n = idx4 / HWSZ;
    int p = idx4 - n * HWSZ;
    const float* base = image + (size_t)n * CC * HWSZ;
    v4f c0 = __builtin_nontemporal_load((const v4f*)(base + p));
    v4f c1 = __builtin_nontemporal_load((const v4f*)(base + HWSZ + p));
    v4f c2 = __builtin_nontemporal_load((const v4f*)(base + 2 * HWSZ + p));
    v8u o0 = { f2bf(c0.x), f2bf(c1.x), f2bf(c2.x), 0,
               f2bf(c0.y), f2bf(c1.y), f2bf(c2.y), 0 };
    v8u o1 = { f2bf(c0.z), f2bf(c1.z), f2bf(c2.z), 0,
               f2bf(c0.w), f2bf(c1.w), f2bf(c2.w), 0 };
    // cached stores on purpose: ws should land in L2/L3 for the warp pass
    unsigned short* w = ws + (size_t)idx4 * 4;
    *(v8u*)(w)     = o0;
    *(v8u*)(w + 8) = o1;
}

// ---- pass 2: warp from bf16 NHWC, 4 px/thread, 64x16 tile/block ----
// grid = NN*HWSZ/1024 = 6144 blocks; XCD-slab swizzle on low 3 bits.
__global__ __launch_bounds__(256) void warp_kernel(
    const unsigned short* __restrict__ ws,
    const float* __restrict__ flow,
    float* __restrict__ out)
{
    int bid  = blockIdx.x;
    int slot = bid >> 3;                   // 0..767 within XCD slab
    int img  = slot / 192;                 // 192 tiles per image (8x24)
    int tile = slot - img * 192;
    int n    = (bid & 7) * 4 + img;        // 4 images per XCD slab
    int ty   = tile >> 3;                  // 24 tile-rows (16 px tall)
    int tx   = tile & 7;                   // 8 tile-cols (64 px wide)

    int r = (int)threadIdx.x >> 4;                  // 0..15 row within tile
    int y = ty * 16 + r;
    int x = (tx << 6) + (((int)threadIdx.x & 15) << 2); // 4 px per thread
    int p = y * WW + x;

    const float* fl = flow + (size_t)n * 2 * HWSZ;
    v4f fu4 = __builtin_nontemporal_load((const v4f*)(fl + p));
    v4f fv4 = __builtin_nontemporal_load((const v4f*)(fl + HWSZ + p));

    const unsigned short* wb = ws + (size_t)n * HWSZ * 4;
    float*                o  = out + (size_t)n * CC * HWSZ;

    // ---- fully scalarized per-pixel address/weight computation ----
#define ADDR(i)                                                               \
    unsigned long long ga_##i, gb_##i; float wx0_##i, wx1_##i, ev_##i, dv_##i;\
    {                                                                         \
        float u  = (float)(x + i) + fu4[i] * (float)WW;                       \
        float v  = (float)y       + fv4[i] * (float)HH;                       \
        float u0 = floorf(u), v0 = floorf(v);                                 \
        float du = u - u0,    dvf = v - v0;                                   \
        int u0i = (int)u0, v0i = (int)v0;                                     \
        bool valid = (u >= 0.f) && (u <= (float)(WW - 1)) &&                  \
                     (v >= 0.f) && (v <= (float)(HH - 1));                    \
        int x0 = min(max(u0i,     0), WW - 1);                                \
        int x1 = min(max(u0i + 1, 0), WW - 1);                                \
        int xb = min(x0, WW - 2);        /* 16B pair never crosses row end */ \
        int y0 = min(max(v0i,     0), HH - 1);                                \
        int y1 = min(max(v0i + 1, 0), HH - 1);                                \
        float eu = 1.f - du;                                                  \
        float w0 = ((x0 > xb) ? 0.f : eu) + ((x1 > xb) ? 0.f : du);           \
        wx0_##i = w0;                                                         \
        wx1_##i = 1.f - w0;              /* eu+du == 1 */                     \
        float evq = 1.f - dvf;                                                \
        ev_##i = valid ? evq : 0.f;      /* fold border-zero into weights */  \
        dv_##i = valid ? dvf : 0.f;                                           \
        ga_##i = (unsigned long long)(wb + (size_t)(y0 * WW + xb) * 4);       \
        gb_##i = (unsigned long long)(wb + (size_t)(y1 * WW + xb) * 4);       \
    }

    ADDR(0) ADDR(1) ADDR(2) ADDR(3)

    // ---- ONE asm block: 8 gathers + drain. Atomic to the compiler: no
    // spill/reorder windows; all 8 results forced simultaneously live. ----
    v4u A0, B0, A1, B1, A2, B2, A3, B3;
    asm volatile(
        "global_load_dwordx4 %0, %8,  off\n\t"
        "global_load_dwordx4 %1, %9,  off\n\t"
        "global_load_dwordx4 %2, %10, off\n\t"
        "global_load_dwordx4 %3, %11, off\n\t"
        "global_load_dwordx4 %4, %12, off\n\t"
        "global_load_dwordx4 %5, %13, off\n\t"
        "global_load_dwordx4 %6, %14, off\n\t"
        "global_load_dwordx4 %7, %15, off\n\t"
        "s_waitcnt vmcnt(0)"
        : "=&v"(A0), "=&v"(B0), "=&v"(A1), "=&v"(B1),
          "=&v"(A2), "=&v"(B2), "=&v"(A3), "=&v"(B3)
        : "v"(ga_0), "v"(gb_0), "v"(ga_1), "v"(gb_1),
          "v"(ga_2), "v"(gb_2), "v"(ga_3), "v"(gb_3));
    __builtin_amdgcn_sched_barrier(0);

    // dword layout per 16B: d0 = c1<<16|c0, d1 = c2, d2 = c1'<<16|c0', d3 = c2'
    v4f r0, r1, r2;
#define BLEND(i, Ai, Bi)                                                      \
    {                                                                         \
        float aL, aH, bL, bH, ra, rb;                                         \
        aL = bflo(Ai.x); aH = bflo(Ai.z);                                     \
        bL = bflo(Bi.x); bH = bflo(Bi.z);                                     \
        ra = wx0_##i * aL + wx1_##i * aH;                                     \
        rb = wx0_##i * bL + wx1_##i * bH;                                     \
        r0[i] = ra * ev_##i + rb * dv_##i;                                    \
        aL = bfhi(Ai.x); aH = bfhi(Ai.z);                                     \
        bL = bfhi(Bi.x); bH = bfhi(Bi.z);                                     \
        ra = wx0_##i * aL + wx1_##i * aH;                                     \
        rb = wx0_##i * bL + wx1_##i * bH;                                     \
        r1[i] = ra * ev_##i + rb * dv_##i;                                    \
        aL = bflo(Ai.y); aH = bflo(Ai.w);                                     \
        bL = bflo(Bi.y); bH = bflo(Bi.w);                                     \
        ra = wx0_##i * aL + wx1_##i * aH;                                     \
        rb = wx0_##i * bL + wx1_##i * bH;                                     \
        r2[i] = ra * ev_##i + rb * dv_##i;                                    \
    }

    BLEND(0, A0, B0)
    BLEND(1, A1, B1)
    BLEND(2, A2, B2)
    BLEND(3, A3, B3)

    __builtin_nontemporal_store(r0, (v4f*)(o + p));
    __builtin_nontemporal_store(r1, (v4f*)(o + HWSZ + p));
    __builtin_nontemporal_store(r2, (v4f*)(o + 2 * HWSZ + p));
#undef ADDR
#undef BLEND
}

// ---- fallback (R3 kernel) if ws is too small ----
__global__ __launch_bounds__(256) void warp_fb(
    const float* __restrict__ image,
    const float* __restrict__ flow,
    float* __restrict__ out)
{
    int bid  = blockIdx.x;
    int slot = bid >> 3;
    int img  = slot / (HWSZ / 1024);
    int wi   = slot - img * (HWSZ / 1024);
    int n    = (bid & 7) * 4 + img;

    int p = wi * 1024 + (int)threadIdx.x * 4;
    int y = p >> 9;
    int x = p & (WW - 1);

    const float* fl = flow + (size_t)n * 2 * HWSZ;
    v4f fu4 = __builtin_nontemporal_load((const v4f*)(fl + p));
    v4f fv4 = __builtin_nontemporal_load((const v4f*)(fl + HWSZ + p));

    float u[4] = { (float)(x + 0) + fu4.x * (float)WW,
                   (float)(x + 1) + fu4.y * (float)WW,
                   (float)(x + 2) + fu4.z * (float)WW,
                   (float)(x + 3) + fu4.w * (float)WW };
    float v[4] = { (float)y + fv4.x * (float)HH,
                   (float)y + fv4.y * (float)HH,
                   (float)y + fv4.z * (float)HH,
                   (float)y + fv4.w * (float)HH };
    int rb0[4], rb1[4];
    float w00[4], w10[4], w01[4], w11[4];
    bool hi0[4], hi1[4], valid[4];
#pragma unroll
    for (int i = 0; i < 4; ++i) {
        float u0 = floorf(u[i]), v0 = floorf(v[i]);
        float du = u[i] - u0, dv = v[i] - v0;
        int u0i = (int)u0, v0i = (int)v0;
        valid[i] = (u[i] >= 0.f) && (u[i] <= (float)(WW - 1)) &&
                   (v[i] >= 0.f) && (v[i] <= (float)(HH - 1));
        int x0 = min(max(u0i, 0), WW - 1);
        int x1 = min(max(u0i + 1, 0), WW - 1);
        int xb = min(x0, WW - 2);
        int y0 = min(max(v0i, 0), HH - 1);
        int y1 = min(max(v0i + 1, 0), HH - 1);
        rb0[i] = y0 * WW + xb; rb1[i] = y1 * WW + xb;
        hi0[i] = (x0 > xb); hi1[i] = (x1 > xb);
        float eu = 1.f - du, ev = 1.f - dv;
        w00[i] = eu * ev; w10[i] = du * ev; w01[i] = eu * dv; w11[i] = du * dv;
    }
    const float* imb = image + (size_t)n * CC * HWSZ;
    float*       o   = out   + (size_t)n * CC * HWSZ;
    v2f a[CC][4], b[CC][4];
#pragma unroll
    for (int c = 0; c < CC; ++c) {
        const float* ic = imb + c * HWSZ;
#pragma unroll
        for (int i = 0; i < 4; ++i) {
            a[c][i] = *(const v2f*)(ic + rb0[i]);
            b[c][i] = *(const v2f*)(ic + rb1[i]);
        }
    }
#pragma unroll
    for (int c = 0; c < CC; ++c) {
        v4f r;
#pragma unroll
        for (int i = 0; i < 4; ++i) {
            float g00 = hi0[i] ? a[c][i].y : a[c][i].x;
            float g10 = hi1[i] ? a[c][i].y : a[c][i].x;
            float g01 = hi0[i] ? b[c][i].y : b[c][i].x;
            float g11 = hi1[i] ? b[c][i].y : b[c][i].x;
            float res = w00[i] * g00 + w10[i] * g10 + w01[i] * g01 + w11[i] * g11;
            r[i] = valid[i] ? res : 0.f;
        }
        __builtin_nontemporal_store(r, (v4f*)(o + c * HWSZ + p));
    }
}

extern "C" void kernel_launch(void* const* d_in, const int* in_sizes, int n_in,
                              void* d_out, int out_size, void* d_ws, size_t ws_size,
                              hipStream_t stream) {
    const float* image = (const float*)d_in[0];
    const float* flow  = (const float*)d_in[1];
    float* out = (float*)d_out;

    const size_t need = (size_t)NN * HWSZ * 4 * sizeof(unsigned short); // 50.3 MB
    if (ws_size >= need) {
        unsigned short* ws = (unsigned short*)d_ws;
        prep_kernel<<<NN * HWSZ / (256 * 4), 256, 0, stream>>>(image, ws);
        warp_kernel<<<NN * HWSZ / 1024, 256, 0, stream>>>(ws, flow, out); // 6144 blocks
    } else {
        warp_fb<<<NN * HWSZ / 1024, 256, 0, stream>>>(image, flow, out);
    }
}